// Round 8
// baseline (353.800 us; speedup 1.0000x reference)
//
#include <hip/hip_runtime.h>

#define N_NODES 50000
#define N_EDGES 800000
#define N_GRAPHS 128
#define IN_DIM 128
#define HID 256
#define H2 128
#define OUT_DIM 10
#define BN_EPS 1e-5f

#define NBUCK 196                              // dst>>8 buckets (50000/256)
#define K1_ITEMS 2048
#define NB_EDGE ((N_EDGES + K1_ITEMS - 1) / K1_ITEMS)   // 391
#define BND_BLOCKS ((N_NODES + 255) / 256)     // 196
#define CW1_BLOCKS  ((IN_DIM * HID) / 256)     // 128
#define CW2_BLOCKS  ((HID * H2) / 256)         // 128
#define CW3_BLOCKS  ((H2 * H2) / 256)          // 64

typedef __attribute__((ext_vector_type(8))) short short8_t;   // 8 bf16 (4 VGPRs)
typedef __attribute__((ext_vector_type(4))) float f32x4;

__device__ __forceinline__ unsigned short f2bf(float f) {
    union { float f; unsigned u; } x; x.f = f;
    unsigned r = x.u + 0x7fffu + ((x.u >> 16) & 1u);   // round-to-nearest-even
    return (unsigned short)(r >> 16);
}
__device__ __forceinline__ float bf2f(unsigned short h) {
    union { unsigned u; float f; } x; x.u = ((unsigned)h) << 16;
    return x.f;
}
__device__ __forceinline__ unsigned pack2(float a, float b) {
    return (unsigned)f2bf(a) | ((unsigned)f2bf(b) << 16);
}

__device__ __forceinline__ void convw_body(const float* __restrict__ W,
        unsigned short* __restrict__ WT, int K, int NOUT, int i) {
    int k = i / NOUT, n = i - k * NOUT;
    WT[(size_t)n * K + k] = f2bf(W[i]);
}

// ---- K1: per-block LDS histograms of dst>>8 and src>>8 | convw x3 | graph bounds ----
__global__ __launch_bounds__(256) void k1_hist(const int* __restrict__ src,
        const int* __restrict__ dst, int* __restrict__ cntD, int* __restrict__ cntS,
        const float* __restrict__ W1, const float* __restrict__ W2, const float* __restrict__ W3,
        unsigned short* __restrict__ W1T, unsigned short* __restrict__ W2T,
        unsigned short* __restrict__ W3T,
        const int* __restrict__ gid, int* __restrict__ gstart) {
    int bid = blockIdx.x, tid = threadIdx.x;
    if (bid < NB_EDGE) {
        __shared__ int hD[256], hS[256];
        hD[tid] = 0; hS[tid] = 0;
        __syncthreads();
        int base = bid * K1_ITEMS;
#pragma unroll
        for (int it = 0; it < 8; it++) {
            int e = base + it * 256 + tid;
            if (e < N_EDGES) {
                atomicAdd(&hD[dst[e] >> 8], 1);
                atomicAdd(&hS[src[e] >> 8], 1);
            }
        }
        __syncthreads();
        cntD[bid * 256 + tid] = hD[tid];
        cntS[bid * 256 + tid] = hS[tid];
        return;
    }
    bid -= NB_EDGE;
    if (bid < CW1_BLOCKS) { convw_body(W1, W1T, IN_DIM, HID, bid * 256 + tid); return; }
    bid -= CW1_BLOCKS;
    if (bid < CW2_BLOCKS) { convw_body(W2, W2T, HID, H2, bid * 256 + tid); return; }
    bid -= CW2_BLOCKS;
    if (bid < CW3_BLOCKS) { convw_body(W3, W3T, H2, H2, bid * 256 + tid); return; }
    bid -= CW3_BLOCKS;
    {   // graph segment starts (graph_ids sorted)
        int n = bid * 256 + tid;
        if (n >= N_NODES) return;
        int g = gid[n];
        int gp = (n == 0) ? -1 : gid[n - 1];
        for (int k = gp + 1; k <= g; k++) gstart[k] = n;
        if (n == N_NODES - 1)
            for (int k = g + 1; k <= N_GRAPHS; k++) gstart[k] = N_NODES;
    }
}

// ---- K2: scan count tables -> per-(block,bucket) offsets + bucket bases ----
__global__ __launch_bounds__(256) void k2_scan(const int* __restrict__ cntD,
        const int* __restrict__ cntS, int* __restrict__ offD, int* __restrict__ offS,
        int* __restrict__ baseD, int* __restrict__ baseS, int* __restrict__ rowptr) {
    int b = threadIdx.x;
    int runD = 0, runS = 0;
    for (int blk = 0; blk < NB_EDGE; blk++) {
        int cD = cntD[blk * 256 + b]; offD[blk * 256 + b] = runD; runD += cD;
        int cS = cntS[blk * 256 + b]; offS[blk * 256 + b] = runS; runS += cS;
    }
    __shared__ int ldsD[256], ldsS[256];
    ldsD[b] = runD; ldsS[b] = runS;
    __syncthreads();
    for (int off = 1; off < 256; off <<= 1) {
        int uD = (b >= off) ? ldsD[b - off] : 0;
        int uS = (b >= off) ? ldsS[b - off] : 0;
        __syncthreads();
        ldsD[b] += uD; ldsS[b] += uS;
        __syncthreads();
    }
    baseD[b] = ldsD[b] - runD;
    baseS[b] = ldsS[b] - runS;
    if (b == 0) rowptr[N_NODES] = N_EDGES;
}

// ---- K3: scatter edges into dst-buckets (uint2{dst,src}) and src-buckets (src) ----
__global__ __launch_bounds__(256) void k3_scatter(const int* __restrict__ src,
        const int* __restrict__ dst, const int* __restrict__ offD, const int* __restrict__ offS,
        const int* __restrict__ baseD, const int* __restrict__ baseS,
        uint2* __restrict__ bufD, int* __restrict__ bufS) {
    __shared__ int cD[256], cS[256];
    int bid = blockIdx.x, tid = threadIdx.x;
    cD[tid] = baseD[tid] + offD[bid * 256 + tid];
    cS[tid] = baseS[tid] + offS[bid * 256 + tid];
    __syncthreads();
    int base = bid * K1_ITEMS;
#pragma unroll
    for (int it = 0; it < 8; it++) {
        int e = base + it * 256 + tid;
        if (e < N_EDGES) {
            int d = dst[e], s = src[e];
            int pd = atomicAdd(&cD[d >> 8], 1);
            bufD[pd] = make_uint2((unsigned)d, (unsigned)s);
            int ps = atomicAdd(&cS[s >> 8], 1);
            bufS[ps] = s;
        }
    }
}

// ---- K4: per dst-bucket: indeg, rowptr, csr_src (contiguous streams, LDS only) ----
__global__ __launch_bounds__(256) void k4_csr(const uint2* __restrict__ bufD,
        const int* __restrict__ baseD, int* __restrict__ indeg,
        int* __restrict__ rowptr, int* __restrict__ csr_src) {
    __shared__ int cnt[256], lds[256], curs[256];
    int b = blockIdx.x, t = threadIdx.x;
    int eb = baseD[b], ee = baseD[b + 1];
    cnt[t] = 0;
    __syncthreads();
    for (int e = eb + t; e < ee; e += 256)
        atomicAdd(&cnt[bufD[e].x & 255], 1);
    __syncthreads();
    int v = cnt[t];
    lds[t] = v;
    __syncthreads();
    for (int off = 1; off < 256; off <<= 1) {
        int u = (t >= off) ? lds[t - off] : 0;
        __syncthreads();
        lds[t] += u;
        __syncthreads();
    }
    int n0 = b << 8;
    int ex = eb + lds[t] - v;
    if (n0 + t < N_NODES) {
        indeg[n0 + t] = v;
        rowptr[n0 + t] = ex;
    }
    curs[t] = ex;
    __syncthreads();
    for (int e = eb + t; e < ee; e += 256) {
        uint2 ed = bufD[e];
        int slot = atomicAdd(&curs[ed.x & 255], 1);
        csr_src[slot] = (int)ed.y;
    }
}

// ---- K5: per src-bucket: outdeg histogram + fused n_feat prescale -> Xs bf16 ----
__global__ __launch_bounds__(256) void k5_outdeg_prescale(const int* __restrict__ bufS,
        const int* __restrict__ baseS, const float* __restrict__ n_feat,
        int* __restrict__ outdeg, unsigned int* __restrict__ Xs) {
    __shared__ int cnt[256];
    __shared__ float od[256];
    int b = blockIdx.x, t = threadIdx.x;
    int eb = baseS[b], ee = baseS[b + 1];
    cnt[t] = 0;
    __syncthreads();
    for (int e = eb + t; e < ee; e += 256)
        atomicAdd(&cnt[bufS[e] & 255], 1);
    __syncthreads();
    int n0 = b << 8;
    int nn = min(256, N_NODES - n0);
    if (t < nn) outdeg[n0 + t] = cnt[t];
    od[t] = rsqrtf(fmaxf((float)cnt[t], 1.0f));
    __syncthreads();
    int pc = t & 127;       // pair-column
    int rh = t >> 7;        // row parity
    for (int r = rh; r < nn; r += 2) {
        int row = n0 + r;
        float2 v = *reinterpret_cast<const float2*>(n_feat + (size_t)row * 128 + pc * 2);
        float s = od[r];
        Xs[(size_t)row * 64 + pc] = pack2(v.x * s, v.y * s);
    }
}

// ---- pull aggregation: XCD-local column quarter, 8 lanes/edge, 8 edges/load ----
// quarter q = (blockIdx%8)>>1 -> each XCD pair only touches a 3.2MB column slice
// (L2-resident). Wave: lane = eslot*8 + c8; eslot picks edge, c8 picks 8B chunk.
// MODE 0: out = bf16(acc * id)
// MODE 1: out = bf16(relu(acc*id + bias) * od)   (pre-scales for next layer)
template<int MODE>
__global__ __launch_bounds__(256) void pull_agg(const unsigned int* __restrict__ X,
        const int* __restrict__ rowptr, const int* __restrict__ csr_src,
        const int* __restrict__ indeg, const int* __restrict__ outdeg,
        const float* __restrict__ bias, unsigned int* __restrict__ out) {
    int b = blockIdx.x;
    int q = (b & 7) >> 1;                 // column quarter, pinned per XCD pair
    int wave = threadIdx.x >> 6;
    int lane = threadIdx.x & 63;
    int eslot = lane >> 3;                // which of 8 concurrent edges
    int c8 = lane & 7;                    // 8B chunk within 64B quarter-row
    int qoff = q * 16 + c8 * 2;           // uint offset within 64-uint row

    int wid_in_q = (b >> 3) * 2 + (b & 1);          // 0..(gridDim/4)
    int nstride = (gridDim.x >> 2) * 4;             // nodes per sweep

    for (int n0 = wid_in_q * 4 + wave; n0 < N_NODES; n0 += nstride) {
        int n = __builtin_amdgcn_readfirstlane(n0);   // wave-uniform -> scalar loads
        int beg = rowptr[n];
        int cnt = rowptr[n + 1] - beg;
        const int* ep = csr_src + beg;
        float a0 = 0.f, a1 = 0.f, a2 = 0.f, a3 = 0.f;

        int j = 0;
        for (; j + 32 <= cnt; j += 32) {
            uint2 u[4];
#pragma unroll
            for (int t = 0; t < 4; t++) {
                int s = ep[j + t * 8 + eslot];
                u[t] = *reinterpret_cast<const uint2*>(X + ((size_t)s << 6) + qoff);
            }
#pragma unroll
            for (int t = 0; t < 4; t++) {
                a0 += bf2f((unsigned short)(u[t].x & 0xffff));
                a1 += bf2f((unsigned short)(u[t].x >> 16));
                a2 += bf2f((unsigned short)(u[t].y & 0xffff));
                a3 += bf2f((unsigned short)(u[t].y >> 16));
            }
        }
        for (; j < cnt; j += 8) {
            int jj = j + eslot;
            int s = ep[min(jj, cnt - 1)];
            uint2 u = *reinterpret_cast<const uint2*>(X + ((size_t)s << 6) + qoff);
            if (jj < cnt) {
                a0 += bf2f((unsigned short)(u.x & 0xffff));
                a1 += bf2f((unsigned short)(u.x >> 16));
                a2 += bf2f((unsigned short)(u.y & 0xffff));
                a3 += bf2f((unsigned short)(u.y >> 16));
            }
        }

        // fold the 8 edge-slots (strides 8,16,32)
#pragma unroll
        for (int d = 8; d < 64; d <<= 1) {
            a0 += __shfl_xor(a0, d);
            a1 += __shfl_xor(a1, d);
            a2 += __shfl_xor(a2, d);
            a3 += __shfl_xor(a3, d);
        }

        if (eslot == 0) {
            float id = rsqrtf(fmaxf((float)indeg[n], 1.0f));
            float v0 = a0 * id, v1 = a1 * id, v2 = a2 * id, v3 = a3 * id;
            if (MODE == 1) {
                float odv = rsqrtf(fmaxf((float)outdeg[n], 1.0f));
                float4 bv = *reinterpret_cast<const float4*>(bias + q * 32 + c8 * 4);
                v0 = fmaxf(v0 + bv.x, 0.f) * odv;
                v1 = fmaxf(v1 + bv.y, 0.f) * odv;
                v2 = fmaxf(v2 + bv.z, 0.f) * odv;
                v3 = fmaxf(v3 + bv.w, 0.f) * odv;
            }
            uint2 o = make_uint2(pack2(v0, v1), pack2(v2, v3));
            *reinterpret_cast<uint2*>(out + (size_t)n * 64 + qoff) = o;
        }
    }
}

// ---------------- MFMA bf16 GEMM, B-resident-in-registers, A streamed ----------------
// out[M,NOUT] = A[M,K] @ W[K,NOUT].  WT: bf16 [NOUT][K] (= W^T).
// EPI 1: bias+relu (aux=bias[NOUT])   EPI 2: row-scale by rsqrt(outdeg) (auxi=outdeg)
// F32OUT: write float (numeric headroom for the pooled layer).
template<int K, int NOUT, int EPI, bool F32OUT>
__global__ __launch_bounds__(256) void mfma_gemm(const unsigned short* __restrict__ A,
        const unsigned short* __restrict__ WT, const float* __restrict__ aux,
        const int* __restrict__ auxi, void* __restrict__ outv) {
    constexpr int KK  = K / 32;      // MFMA k-steps
    constexpr int NBW = NOUT / 64;   // 16-col blocks per wave (4 or 2)
    int wave = threadIdx.x >> 6;
    int lane = threadIdx.x & 63;
    int col0 = lane & 15;
    int kgrp = (lane >> 4) * 8;
    int wcol = wave * NBW * 16;

    short8_t b[NBW][KK];
    {
        const unsigned short* wbase = WT + (size_t)(wcol + col0) * K + kgrp;
#pragma unroll
        for (int n = 0; n < NBW; n++)
#pragma unroll
            for (int kk = 0; kk < KK; kk++)
                b[n][kk] = *reinterpret_cast<const short8_t*>(
                    wbase + (size_t)n * 16 * K + kk * 32);
    }
    float bv[NBW];
    if (EPI == 1) {
#pragma unroll
        for (int n = 0; n < NBW; n++) bv[n] = aux[wcol + n * 16 + col0];
    }

    constexpr int NT = N_NODES / 16;   // 3125 row tiles, exact
    for (int rt = blockIdx.x; rt < NT; rt += gridDim.x) {
        const unsigned short* ap = A + (size_t)(rt * 16 + col0) * K + kgrp;
        short8_t a[KK];
#pragma unroll
        for (int kk = 0; kk < KK; kk++)
            a[kk] = *reinterpret_cast<const short8_t*>(ap + kk * 32);

        f32x4 acc[NBW];
#pragma unroll
        for (int n = 0; n < NBW; n++) acc[n] = f32x4{0.f, 0.f, 0.f, 0.f};
#pragma unroll
        for (int kk = 0; kk < KK; kk++)
#pragma unroll
            for (int n = 0; n < NBW; n++)
                acc[n] = __builtin_amdgcn_mfma_f32_16x16x32_bf16(a[kk], b[n][kk], acc[n], 0, 0, 0);

        // C/D layout: col = lane&15, row = (lane>>4)*4 + reg
        int rbase = rt * 16 + ((lane >> 4) << 2);
        float rs[4];
        if (EPI == 2) {
#pragma unroll
            for (int j = 0; j < 4; j++)
                rs[j] = rsqrtf(fmaxf((float)auxi[rbase + j], 1.0f));
        }
#pragma unroll
        for (int n = 0; n < NBW; n++) {
            int col = wcol + n * 16 + col0;
#pragma unroll
            for (int j = 0; j < 4; j++) {
                float v = acc[n][j];
                if (EPI == 1) v = fmaxf(v + bv[n], 0.f);
                if (EPI == 2) v = v * rs[j];
                if (F32OUT)
                    ((float*)outv)[(size_t)(rbase + j) * NOUT + col] = v;
                else
                    ((unsigned short*)outv)[(size_t)(rbase + j) * NOUT + col] = f2bf(v);
            }
        }
    }
}

// ---------------- sum pooling over contiguous segments (f32 in, f32 out) ----------
__global__ __launch_bounds__(512) void seg_pool(const float* __restrict__ X,
        const int* __restrict__ gstart, float* __restrict__ emb) {
    int g = blockIdx.x;
    int lane = threadIdx.x & 63;      // 2 cols per lane
    int stripe = threadIdx.x >> 6;    // 0..7
    int beg = gstart[g], end = gstart[g + 1];
    float ax = 0.f, ay = 0.f;
    for (int r = beg + stripe; r < end; r += 8) {
        float2 v = *reinterpret_cast<const float2*>(X + (size_t)r * 128 + lane * 2);
        ax += v.x; ay += v.y;
    }
    __shared__ float bufx[8][64], bufy[8][64];
    bufx[stripe][lane] = ax;
    bufy[stripe][lane] = ay;
    __syncthreads();
    if (stripe == 0) {
        float sx = 0.f, sy = 0.f;
#pragma unroll
        for (int q = 0; q < 8; q++) { sx += bufx[q][lane]; sy += bufy[q][lane]; }
        emb[g * 128 + lane * 2]     = sx;
        emb[g * 128 + lane * 2 + 1] = sy;
    }
}

// ---------------- fused BN + FC head + log_softmax ----------------
__global__ __launch_bounds__(128) void fc_kernel(const float* __restrict__ emb,
        const float* __restrict__ gamma, const float* __restrict__ beta,
        const float* __restrict__ Wf1, const float* __restrict__ bf1,
        const float* __restrict__ Wf2, const float* __restrict__ bf2,
        float* __restrict__ out_ls) {
    __shared__ float h[H2];
    __shared__ float logits[OUT_DIM];
    int g = blockIdx.x;
    int j = threadIdx.x;
    float s = 0.f;
    for (int q = 0; q < N_GRAPHS; q++) s += emb[q * 128 + j];
    float mean = s * (1.0f / N_GRAPHS);
    float v = 0.f;
    for (int q = 0; q < N_GRAPHS; q++) {
        float d = emb[q * 128 + j] - mean;
        v += d * d;
    }
    v *= (1.0f / N_GRAPHS);
    float scale = rsqrtf(v + BN_EPS) * gamma[j];
    h[j] = (emb[g * 128 + j] - mean) * scale + beta[j];
    __syncthreads();
    float acc = bf1[j];
    for (int k = 0; k < H2; k++) acc += h[k] * Wf1[k * H2 + j];
    __syncthreads();
    h[j] = fmaxf(acc, 0.f);
    __syncthreads();
    if (j < OUT_DIM) {
        float a2 = bf2[j];
        for (int k = 0; k < H2; k++) a2 += h[k] * Wf2[k * OUT_DIM + j];
        logits[j] = a2;
    }
    __syncthreads();
    if (j < OUT_DIM) {
        float m = -1e30f;
        for (int o = 0; o < OUT_DIM; o++) m = fmaxf(m, logits[o]);
        float se = 0.f;
        for (int o = 0; o < OUT_DIM; o++) se += expf(logits[o] - m);
        out_ls[g * OUT_DIM + j] = logits[j] - m - logf(se);
    }
}

extern "C" void kernel_launch(void* const* d_in, const int* in_sizes, int n_in,
                              void* d_out, int out_size, void* d_ws, size_t ws_size,
                              hipStream_t stream) {
    const float* n_feat = (const float*)d_in[0];
    const int*   src    = (const int*)d_in[1];
    const int*   dst    = (const int*)d_in[2];
    const int*   gid    = (const int*)d_in[3];
    const float* W1     = (const float*)d_in[4];
    const float* b1     = (const float*)d_in[5];
    const float* W2     = (const float*)d_in[6];
    const float* b2     = (const float*)d_in[7];
    const float* W3     = (const float*)d_in[8];
    const float* b3     = (const float*)d_in[9];
    const float* Wf1    = (const float*)d_in[10];
    const float* bf1    = (const float*)d_in[11];
    const float* Wf2    = (const float*)d_in[12];
    const float* bf2    = (const float*)d_in[13];
    const float* gamma  = (const float*)d_in[14];
    const float* beta   = (const float*)d_in[15];
    float* out = (float*)d_out;

    char* ws = (char*)d_ws;
    size_t off = 0;
    auto alloc = [&](size_t bytes) {
        void* p = ws + off;
        off = (off + bytes + 255) & ~(size_t)255;
        return p;
    };
    int* cntD    = (int*)alloc((size_t)NB_EDGE * 256 * 4);
    int* cntS    = (int*)alloc((size_t)NB_EDGE * 256 * 4);
    int* offD    = (int*)alloc((size_t)NB_EDGE * 256 * 4);
    int* offS    = (int*)alloc((size_t)NB_EDGE * 256 * 4);
    int* baseD   = (int*)alloc(257 * 4);
    int* baseS   = (int*)alloc(257 * 4);
    int* indeg   = (int*)alloc((size_t)N_NODES * 4);
    int* outdeg  = (int*)alloc((size_t)N_NODES * 4);
    int* rowptr  = (int*)alloc((size_t)(N_NODES + 1) * 4);
    int* gstart  = (int*)alloc((size_t)(N_GRAPHS + 1) * 4);
    uint2* bufD  = (uint2*)alloc((size_t)N_EDGES * 8);
    int* bufS    = (int*)alloc((size_t)N_EDGES * 4);
    int* csr_src = (int*)alloc((size_t)N_EDGES * 4);
    unsigned short* Xs  = (unsigned short*)alloc((size_t)N_NODES * 128 * 2);
    unsigned short* A   = (unsigned short*)alloc((size_t)N_NODES * 128 * 2);
    unsigned short* B   = (unsigned short*)alloc((size_t)N_NODES * 256 * 2);  // also f32 [N,128]
    unsigned short* W1T = (unsigned short*)alloc((size_t)IN_DIM * HID * 2);
    unsigned short* W2T = (unsigned short*)alloc((size_t)HID * H2 * 2);
    unsigned short* W3T = (unsigned short*)alloc((size_t)H2 * H2 * 2);
    float* Bf32 = (float*)B;   // N*256*2 bytes == N*128*4 bytes

    // preprocessing: zero global atomics
    k1_hist<<<NB_EDGE + CW1_BLOCKS + CW2_BLOCKS + CW3_BLOCKS + BND_BLOCKS, 256, 0, stream>>>(
        src, dst, cntD, cntS, W1, W2, W3, W1T, W2T, W3T, gid, gstart);
    k2_scan<<<1, 256, 0, stream>>>(cntD, cntS, offD, offS, baseD, baseS, rowptr);
    k3_scatter<<<NB_EDGE, 256, 0, stream>>>(src, dst, offD, offS, baseD, baseS, bufD, bufS);
    k4_csr<<<NBUCK, 256, 0, stream>>>(bufD, baseD, indeg, rowptr, csr_src);
    k5_outdeg_prescale<<<NBUCK, 256, 0, stream>>>(bufS, baseS, n_feat, outdeg,
                                                  (unsigned int*)Xs);

    const int AGG_GRID = 2048;     // 8 XCD slots x 256; quarter pinned per XCD pair
    const int GEMM_GRID = 1024;

    // Layer 1: A = bf16(agg(Xs)·id); B = bf16(relu(A@W1 + b1))  [N,256]
    pull_agg<0><<<AGG_GRID, 256, 0, stream>>>((unsigned int*)Xs, rowptr, csr_src,
                                              indeg, outdeg, nullptr, (unsigned int*)A);
    mfma_gemm<128, 256, 1, false><<<GEMM_GRID, 256, 0, stream>>>(A, W1T, b1, nullptr, B);

    // Layer 2: A = bf16((X1@W2)·od); B = bf16(relu(agg(A)·id + b2)·od)
    mfma_gemm<256, 128, 2, false><<<GEMM_GRID, 256, 0, stream>>>(B, W2T, nullptr, outdeg, A);
    pull_agg<1><<<AGG_GRID, 256, 0, stream>>>((unsigned int*)A, rowptr, csr_src,
                                              indeg, outdeg, b2, (unsigned int*)B);

    // Layer 3: A = bf16(agg(B)·id); Bf32 = relu(A@W3 + b3)  [f32 for pooling accuracy]
    pull_agg<0><<<AGG_GRID, 256, 0, stream>>>((unsigned int*)B, rowptr, csr_src,
                                              indeg, outdeg, nullptr, (unsigned int*)A);
    mfma_gemm<128, 128, 1, true><<<GEMM_GRID, 256, 0, stream>>>(A, W3T, b3, nullptr, Bf32);

    // Readout
    seg_pool<<<N_GRAPHS, 512, 0, stream>>>(Bf32, gstart, out);
    fc_kernel<<<N_GRAPHS, 128, 0, stream>>>(out, gamma, beta, Wf1, bf1, Wf2, bf2,
                                            out + (size_t)N_GRAPHS * H2);
}

// Round 9
// 266.330 us; speedup vs baseline: 1.3284x; 1.3284x over previous
//
#include <hip/hip_runtime.h>

#define N_NODES 50000
#define N_EDGES 800000
#define N_GRAPHS 128
#define IN_DIM 128
#define HID 256
#define H2 128
#define OUT_DIM 10
#define BN_EPS 1e-5f

#define NBUCK 196                              // dst>>8 buckets (50000/256)
#define K1_ITEMS 2048
#define NB_EDGE ((N_EDGES + K1_ITEMS - 1) / K1_ITEMS)   // 391
#define BND_BLOCKS ((N_NODES + 255) / 256)     // 196
#define CW1_BLOCKS  ((IN_DIM * HID) / 256)     // 128
#define CW2_BLOCKS  ((HID * H2) / 256)         // 128
#define CW3_BLOCKS  ((H2 * H2) / 256)          // 64

typedef __attribute__((ext_vector_type(8))) short short8_t;   // 8 bf16 (4 VGPRs)
typedef __attribute__((ext_vector_type(4))) float f32x4;

__device__ __forceinline__ unsigned short f2bf(float f) {
    union { float f; unsigned u; } x; x.f = f;
    unsigned r = x.u + 0x7fffu + ((x.u >> 16) & 1u);   // round-to-nearest-even
    return (unsigned short)(r >> 16);
}
__device__ __forceinline__ float bf2f(unsigned short h) {
    union { unsigned u; float f; } x; x.u = ((unsigned)h) << 16;
    return x.f;
}
__device__ __forceinline__ unsigned pack2(float a, float b) {
    return (unsigned)f2bf(a) | ((unsigned)f2bf(b) << 16);
}

__device__ __forceinline__ void convw_body(const float* __restrict__ W,
        unsigned short* __restrict__ WT, int K, int NOUT, int i) {
    int k = i / NOUT, n = i - k * NOUT;
    WT[(size_t)n * K + k] = f2bf(W[i]);
}

// ---- K1: per-block LDS histograms of dst>>8 and src>>8 | convw x3 | graph bounds ----
__global__ __launch_bounds__(256) void k1_hist(const int* __restrict__ src,
        const int* __restrict__ dst, int* __restrict__ cntD, int* __restrict__ cntS,
        const float* __restrict__ W1, const float* __restrict__ W2, const float* __restrict__ W3,
        unsigned short* __restrict__ W1T, unsigned short* __restrict__ W2T,
        unsigned short* __restrict__ W3T,
        const int* __restrict__ gid, int* __restrict__ gstart) {
    int bid = blockIdx.x, tid = threadIdx.x;
    if (bid < NB_EDGE) {
        __shared__ int hD[256], hS[256];
        hD[tid] = 0; hS[tid] = 0;
        __syncthreads();
        int base = bid * K1_ITEMS;
#pragma unroll
        for (int it = 0; it < 8; it++) {
            int e = base + it * 256 + tid;
            if (e < N_EDGES) {
                atomicAdd(&hD[dst[e] >> 8], 1);
                atomicAdd(&hS[src[e] >> 8], 1);
            }
        }
        __syncthreads();
        cntD[bid * 256 + tid] = hD[tid];
        cntS[bid * 256 + tid] = hS[tid];
        return;
    }
    bid -= NB_EDGE;
    if (bid < CW1_BLOCKS) { convw_body(W1, W1T, IN_DIM, HID, bid * 256 + tid); return; }
    bid -= CW1_BLOCKS;
    if (bid < CW2_BLOCKS) { convw_body(W2, W2T, HID, H2, bid * 256 + tid); return; }
    bid -= CW2_BLOCKS;
    if (bid < CW3_BLOCKS) { convw_body(W3, W3T, H2, H2, bid * 256 + tid); return; }
    bid -= CW3_BLOCKS;
    {   // graph segment starts (graph_ids sorted)
        int n = bid * 256 + tid;
        if (n >= N_NODES) return;
        int g = gid[n];
        int gp = (n == 0) ? -1 : gid[n - 1];
        for (int k = gp + 1; k <= g; k++) gstart[k] = n;
        if (n == N_NODES - 1)
            for (int k = g + 1; k <= N_GRAPHS; k++) gstart[k] = N_NODES;
    }
}

// ---- K2: scan count tables -> per-(block,bucket) offsets + bucket bases ----
__global__ __launch_bounds__(256) void k2_scan(const int* __restrict__ cntD,
        const int* __restrict__ cntS, int* __restrict__ offD, int* __restrict__ offS,
        int* __restrict__ baseD, int* __restrict__ baseS, int* __restrict__ rowptr) {
    int b = threadIdx.x;
    int runD = 0, runS = 0;
    for (int blk = 0; blk < NB_EDGE; blk++) {
        int cD = cntD[blk * 256 + b]; offD[blk * 256 + b] = runD; runD += cD;
        int cS = cntS[blk * 256 + b]; offS[blk * 256 + b] = runS; runS += cS;
    }
    __shared__ int ldsD[256], ldsS[256];
    ldsD[b] = runD; ldsS[b] = runS;
    __syncthreads();
    for (int off = 1; off < 256; off <<= 1) {
        int uD = (b >= off) ? ldsD[b - off] : 0;
        int uS = (b >= off) ? ldsS[b - off] : 0;
        __syncthreads();
        ldsD[b] += uD; ldsS[b] += uS;
        __syncthreads();
    }
    baseD[b] = ldsD[b] - runD;
    baseS[b] = ldsS[b] - runS;
    if (b == 0) rowptr[N_NODES] = N_EDGES;
}

// ---- K3: scatter edges into dst-buckets (uint2{dst,src}) and src-buckets (src) ----
__global__ __launch_bounds__(256) void k3_scatter(const int* __restrict__ src,
        const int* __restrict__ dst, const int* __restrict__ offD, const int* __restrict__ offS,
        const int* __restrict__ baseD, const int* __restrict__ baseS,
        uint2* __restrict__ bufD, int* __restrict__ bufS) {
    __shared__ int cD[256], cS[256];
    int bid = blockIdx.x, tid = threadIdx.x;
    cD[tid] = baseD[tid] + offD[bid * 256 + tid];
    cS[tid] = baseS[tid] + offS[bid * 256 + tid];
    __syncthreads();
    int base = bid * K1_ITEMS;
#pragma unroll
    for (int it = 0; it < 8; it++) {
        int e = base + it * 256 + tid;
        if (e < N_EDGES) {
            int d = dst[e], s = src[e];
            int pd = atomicAdd(&cD[d >> 8], 1);
            bufD[pd] = make_uint2((unsigned)d, (unsigned)s);
            int ps = atomicAdd(&cS[s >> 8], 1);
            bufS[ps] = s;
        }
    }
}

// ---- K4: per dst-bucket: indeg, rowptr, csr_src (contiguous streams, LDS only) ----
__global__ __launch_bounds__(256) void k4_csr(const uint2* __restrict__ bufD,
        const int* __restrict__ baseD, int* __restrict__ indeg,
        int* __restrict__ rowptr, int* __restrict__ csr_src) {
    __shared__ int cnt[256], lds[256], curs[256];
    int b = blockIdx.x, t = threadIdx.x;
    int eb = baseD[b], ee = baseD[b + 1];
    cnt[t] = 0;
    __syncthreads();
    for (int e = eb + t; e < ee; e += 256)
        atomicAdd(&cnt[bufD[e].x & 255], 1);
    __syncthreads();
    int v = cnt[t];
    lds[t] = v;
    __syncthreads();
    for (int off = 1; off < 256; off <<= 1) {
        int u = (t >= off) ? lds[t - off] : 0;
        __syncthreads();
        lds[t] += u;
        __syncthreads();
    }
    int n0 = b << 8;
    int ex = eb + lds[t] - v;
    if (n0 + t < N_NODES) {
        indeg[n0 + t] = v;
        rowptr[n0 + t] = ex;
    }
    curs[t] = ex;
    __syncthreads();
    for (int e = eb + t; e < ee; e += 256) {
        uint2 ed = bufD[e];
        int slot = atomicAdd(&curs[ed.x & 255], 1);
        csr_src[slot] = (int)ed.y;
    }
}

// ---- K5: per src-bucket: outdeg histogram + fused n_feat prescale -> Xs bf16 ----
__global__ __launch_bounds__(256) void k5_outdeg_prescale(const int* __restrict__ bufS,
        const int* __restrict__ baseS, const float* __restrict__ n_feat,
        int* __restrict__ outdeg, unsigned int* __restrict__ Xs) {
    __shared__ int cnt[256];
    __shared__ float od[256];
    int b = blockIdx.x, t = threadIdx.x;
    int eb = baseS[b], ee = baseS[b + 1];
    cnt[t] = 0;
    __syncthreads();
    for (int e = eb + t; e < ee; e += 256)
        atomicAdd(&cnt[bufS[e] & 255], 1);
    __syncthreads();
    int n0 = b << 8;
    int nn = min(256, N_NODES - n0);
    if (t < nn) outdeg[n0 + t] = cnt[t];
    od[t] = rsqrtf(fmaxf((float)cnt[t], 1.0f));
    __syncthreads();
    int pc = t & 127;       // pair-column
    int rh = t >> 7;        // row parity
    for (int r = rh; r < nn; r += 2) {
        int row = n0 + r;
        float2 v = *reinterpret_cast<const float2*>(n_feat + (size_t)row * 128 + pc * 2);
        float s = od[r];
        Xs[(size_t)row * 64 + pc] = pack2(v.x * s, v.y * s);
    }
}

// ---- pull aggregation: wave/node, paired rows, 8B/lane, scalar indices, 8 in flight ----
// MODE 0: out = bf16(acc * id)
// MODE 1: out = bf16(relu(acc*id + bias) * od)   (pre-scales for next layer)
template<int MODE>
__global__ __launch_bounds__(256) void pull_agg(const unsigned int* __restrict__ X,
        const int* __restrict__ rowptr, const int* __restrict__ csr_src,
        const int* __restrict__ indeg, const int* __restrict__ outdeg,
        const float* __restrict__ bias, unsigned int* __restrict__ out) {
    int lane = threadIdx.x & 63;
    int n = blockIdx.x * 4 + (threadIdx.x >> 6);
    n = __builtin_amdgcn_readfirstlane(n);     // wave-uniform -> scalar loads
    if (n >= N_NODES) return;
    int l32 = lane & 31;
    int half = lane >> 5;
    int beg = rowptr[n];
    int cnt = rowptr[n + 1] - beg;
    const int* ep = csr_src + beg;
    float a0 = 0.f, a1 = 0.f, a2 = 0.f, a3 = 0.f;
    int voff = l32 << 1;

    auto acc = [&](uint2 u) {
        a0 += bf2f((unsigned short)(u.x & 0xffff));
        a1 += bf2f((unsigned short)(u.x >> 16));
        a2 += bf2f((unsigned short)(u.y & 0xffff));
        a3 += bf2f((unsigned short)(u.y >> 16));
    };

    int j = 0;
    for (; j + 16 <= cnt; j += 16) {
        uint2 u[8];
#pragma unroll
        for (int q = 0; q < 8; q++) {
            int sa = ep[j + 2 * q], sb = ep[j + 2 * q + 1];
            int s = half ? sb : sa;
            u[q] = *reinterpret_cast<const uint2*>(X + ((size_t)s << 6) + voff);
        }
#pragma unroll
        for (int q = 0; q < 8; q++) acc(u[q]);
    }
    for (; j + 2 <= cnt; j += 2) {
        int sa = ep[j], sb = ep[j + 1];
        int s = half ? sb : sa;
        acc(*reinterpret_cast<const uint2*>(X + ((size_t)s << 6) + voff));
    }
    if (j < cnt && half == 0) {
        int s = ep[j];
        acc(*reinterpret_cast<const uint2*>(X + ((size_t)s << 6) + voff));
    }

    a0 += __shfl_xor(a0, 32);
    a1 += __shfl_xor(a1, 32);
    a2 += __shfl_xor(a2, 32);
    a3 += __shfl_xor(a3, 32);

    if (lane < 32) {
        float id = rsqrtf(fmaxf((float)indeg[n], 1.0f));
        float v0 = a0 * id, v1 = a1 * id, v2 = a2 * id, v3 = a3 * id;
        if (MODE == 1) {
            float odv = rsqrtf(fmaxf((float)outdeg[n], 1.0f));
            float4 bv = *reinterpret_cast<const float4*>(bias + l32 * 4);
            v0 = fmaxf(v0 + bv.x, 0.f) * odv;
            v1 = fmaxf(v1 + bv.y, 0.f) * odv;
            v2 = fmaxf(v2 + bv.z, 0.f) * odv;
            v3 = fmaxf(v3 + bv.w, 0.f) * odv;
        }
        uint2 o = make_uint2(pack2(v0, v1), pack2(v2, v3));
        *reinterpret_cast<uint2*>(out + (size_t)n * 64 + voff) = o;
    }
}

// ---------------- MFMA bf16 GEMM, B-resident-in-registers, A streamed ----------------
// out[M,NOUT] = A[M,K] @ W[K,NOUT].  WT: bf16 [NOUT][K] (= W^T).
// EPI 1: bias+relu (aux=bias[NOUT])   EPI 2: row-scale by rsqrt(outdeg) (auxi=outdeg)
// F32OUT: write float (numeric headroom for the pooled layer).
template<int K, int NOUT, int EPI, bool F32OUT>
__global__ __launch_bounds__(256) void mfma_gemm(const unsigned short* __restrict__ A,
        const unsigned short* __restrict__ WT, const float* __restrict__ aux,
        const int* __restrict__ auxi, void* __restrict__ outv) {
    constexpr int KK  = K / 32;      // MFMA k-steps
    constexpr int NBW = NOUT / 64;   // 16-col blocks per wave (4 or 2)
    int wave = threadIdx.x >> 6;
    int lane = threadIdx.x & 63;
    int col0 = lane & 15;
    int kgrp = (lane >> 4) * 8;
    int wcol = wave * NBW * 16;

    short8_t b[NBW][KK];
    {
        const unsigned short* wbase = WT + (size_t)(wcol + col0) * K + kgrp;
#pragma unroll
        for (int n = 0; n < NBW; n++)
#pragma unroll
            for (int kk = 0; kk < KK; kk++)
                b[n][kk] = *reinterpret_cast<const short8_t*>(
                    wbase + (size_t)n * 16 * K + kk * 32);
    }
    float bv[NBW];
    if (EPI == 1) {
#pragma unroll
        for (int n = 0; n < NBW; n++) bv[n] = aux[wcol + n * 16 + col0];
    }

    constexpr int NT = N_NODES / 16;   // 3125 row tiles, exact
    for (int rt = blockIdx.x; rt < NT; rt += gridDim.x) {
        const unsigned short* ap = A + (size_t)(rt * 16 + col0) * K + kgrp;
        short8_t a[KK];
#pragma unroll
        for (int kk = 0; kk < KK; kk++)
            a[kk] = *reinterpret_cast<const short8_t*>(ap + kk * 32);

        f32x4 acc[NBW];
#pragma unroll
        for (int n = 0; n < NBW; n++) acc[n] = f32x4{0.f, 0.f, 0.f, 0.f};
#pragma unroll
        for (int kk = 0; kk < KK; kk++)
#pragma unroll
            for (int n = 0; n < NBW; n++)
                acc[n] = __builtin_amdgcn_mfma_f32_16x16x32_bf16(a[kk], b[n][kk], acc[n], 0, 0, 0);

        // C/D layout: col = lane&15, row = (lane>>4)*4 + reg
        int rbase = rt * 16 + ((lane >> 4) << 2);
        float rs[4];
        if (EPI == 2) {
#pragma unroll
            for (int j = 0; j < 4; j++)
                rs[j] = rsqrtf(fmaxf((float)auxi[rbase + j], 1.0f));
        }
#pragma unroll
        for (int n = 0; n < NBW; n++) {
            int col = wcol + n * 16 + col0;
#pragma unroll
            for (int j = 0; j < 4; j++) {
                float v = acc[n][j];
                if (EPI == 1) v = fmaxf(v + bv[n], 0.f);
                if (EPI == 2) v = v * rs[j];
                if (F32OUT)
                    ((float*)outv)[(size_t)(rbase + j) * NOUT + col] = v;
                else
                    ((unsigned short*)outv)[(size_t)(rbase + j) * NOUT + col] = f2bf(v);
            }
        }
    }
}

// ---------------- sum pooling over contiguous segments (f32 in, f32 out) ----------
__global__ __launch_bounds__(512) void seg_pool(const float* __restrict__ X,
        const int* __restrict__ gstart, float* __restrict__ emb) {
    int g = blockIdx.x;
    int lane = threadIdx.x & 63;      // 2 cols per lane
    int stripe = threadIdx.x >> 6;    // 0..7
    int beg = gstart[g], end = gstart[g + 1];
    float ax = 0.f, ay = 0.f;
    for (int r = beg + stripe; r < end; r += 8) {
        float2 v = *reinterpret_cast<const float2*>(X + (size_t)r * 128 + lane * 2);
        ax += v.x; ay += v.y;
    }
    __shared__ float bufx[8][64], bufy[8][64];
    bufx[stripe][lane] = ax;
    bufy[stripe][lane] = ay;
    __syncthreads();
    if (stripe == 0) {
        float sx = 0.f, sy = 0.f;
#pragma unroll
        for (int q = 0; q < 8; q++) { sx += bufx[q][lane]; sy += bufy[q][lane]; }
        emb[g * 128 + lane * 2]     = sx;
        emb[g * 128 + lane * 2 + 1] = sy;
    }
}

// ---------------- fused BN + FC head + log_softmax ----------------
__global__ __launch_bounds__(128) void fc_kernel(const float* __restrict__ emb,
        const float* __restrict__ gamma, const float* __restrict__ beta,
        const float* __restrict__ Wf1, const float* __restrict__ bf1,
        const float* __restrict__ Wf2, const float* __restrict__ bf2,
        float* __restrict__ out_ls) {
    __shared__ float h[H2];
    __shared__ float logits[OUT_DIM];
    int g = blockIdx.x;
    int j = threadIdx.x;
    float s = 0.f;
    for (int q = 0; q < N_GRAPHS; q++) s += emb[q * 128 + j];
    float mean = s * (1.0f / N_GRAPHS);
    float v = 0.f;
    for (int q = 0; q < N_GRAPHS; q++) {
        float d = emb[q * 128 + j] - mean;
        v += d * d;
    }
    v *= (1.0f / N_GRAPHS);
    float scale = rsqrtf(v + BN_EPS) * gamma[j];
    h[j] = (emb[g * 128 + j] - mean) * scale + beta[j];
    __syncthreads();
    float acc = bf1[j];
    for (int k = 0; k < H2; k++) acc += h[k] * Wf1[k * H2 + j];
    __syncthreads();
    h[j] = fmaxf(acc, 0.f);
    __syncthreads();
    if (j < OUT_DIM) {
        float a2 = bf2[j];
        for (int k = 0; k < H2; k++) a2 += h[k] * Wf2[k * OUT_DIM + j];
        logits[j] = a2;
    }
    __syncthreads();
    if (j < OUT_DIM) {
        float m = -1e30f;
        for (int o = 0; o < OUT_DIM; o++) m = fmaxf(m, logits[o]);
        float se = 0.f;
        for (int o = 0; o < OUT_DIM; o++) se += expf(logits[o] - m);
        out_ls[g * OUT_DIM + j] = logits[j] - m - logf(se);
    }
}

extern "C" void kernel_launch(void* const* d_in, const int* in_sizes, int n_in,
                              void* d_out, int out_size, void* d_ws, size_t ws_size,
                              hipStream_t stream) {
    const float* n_feat = (const float*)d_in[0];
    const int*   src    = (const int*)d_in[1];
    const int*   dst    = (const int*)d_in[2];
    const int*   gid    = (const int*)d_in[3];
    const float* W1     = (const float*)d_in[4];
    const float* b1     = (const float*)d_in[5];
    const float* W2     = (const float*)d_in[6];
    const float* b2     = (const float*)d_in[7];
    const float* W3     = (const float*)d_in[8];
    const float* b3     = (const float*)d_in[9];
    const float* Wf1    = (const float*)d_in[10];
    const float* bf1    = (const float*)d_in[11];
    const float* Wf2    = (const float*)d_in[12];
    const float* bf2    = (const float*)d_in[13];
    const float* gamma  = (const float*)d_in[14];
    const float* beta   = (const float*)d_in[15];
    float* out = (float*)d_out;

    char* ws = (char*)d_ws;
    size_t off = 0;
    auto alloc = [&](size_t bytes) {
        void* p = ws + off;
        off = (off + bytes + 255) & ~(size_t)255;
        return p;
    };
    int* cntD    = (int*)alloc((size_t)NB_EDGE * 256 * 4);
    int* cntS    = (int*)alloc((size_t)NB_EDGE * 256 * 4);
    int* offD    = (int*)alloc((size_t)NB_EDGE * 256 * 4);
    int* offS    = (int*)alloc((size_t)NB_EDGE * 256 * 4);
    int* baseD   = (int*)alloc(257 * 4);
    int* baseS   = (int*)alloc(257 * 4);
    int* indeg   = (int*)alloc((size_t)N_NODES * 4);
    int* outdeg  = (int*)alloc((size_t)N_NODES * 4);
    int* rowptr  = (int*)alloc((size_t)(N_NODES + 1) * 4);
    int* gstart  = (int*)alloc((size_t)(N_GRAPHS + 1) * 4);
    uint2* bufD  = (uint2*)alloc((size_t)N_EDGES * 8);
    int* bufS    = (int*)alloc((size_t)N_EDGES * 4);
    int* csr_src = (int*)alloc((size_t)N_EDGES * 4);
    unsigned short* Xs  = (unsigned short*)alloc((size_t)N_NODES * 128 * 2);
    unsigned short* A   = (unsigned short*)alloc((size_t)N_NODES * 128 * 2);
    unsigned short* B   = (unsigned short*)alloc((size_t)N_NODES * 256 * 2);  // also f32 [N,128]
    unsigned short* W1T = (unsigned short*)alloc((size_t)IN_DIM * HID * 2);
    unsigned short* W2T = (unsigned short*)alloc((size_t)HID * H2 * 2);
    unsigned short* W3T = (unsigned short*)alloc((size_t)H2 * H2 * 2);
    float* Bf32 = (float*)B;   // N*256*2 bytes == N*128*4 bytes

    // preprocessing: zero global atomics
    k1_hist<<<NB_EDGE + CW1_BLOCKS + CW2_BLOCKS + CW3_BLOCKS + BND_BLOCKS, 256, 0, stream>>>(
        src, dst, cntD, cntS, W1, W2, W3, W1T, W2T, W3T, gid, gstart);
    k2_scan<<<1, 256, 0, stream>>>(cntD, cntS, offD, offS, baseD, baseS, rowptr);
    k3_scatter<<<NB_EDGE, 256, 0, stream>>>(src, dst, offD, offS, baseD, baseS, bufD, bufS);
    k4_csr<<<NBUCK, 256, 0, stream>>>(bufD, baseD, indeg, rowptr, csr_src);
    k5_outdeg_prescale<<<NBUCK, 256, 0, stream>>>(bufS, baseS, n_feat, outdeg,
                                                  (unsigned int*)Xs);

    const int AGG_GRID = (N_NODES + 3) / 4;
    const int GEMM_GRID = 1024;

    // Layer 1: A = bf16(agg(Xs)·id); B = bf16(relu(A@W1 + b1))  [N,256]
    pull_agg<0><<<AGG_GRID, 256, 0, stream>>>((unsigned int*)Xs, rowptr, csr_src,
                                              indeg, outdeg, nullptr, (unsigned int*)A);
    mfma_gemm<128, 256, 1, false><<<GEMM_GRID, 256, 0, stream>>>(A, W1T, b1, nullptr, B);

    // Layer 2: A = bf16((X1@W2)·od); B = bf16(relu(agg(A)·id + b2)·od)
    mfma_gemm<256, 128, 2, false><<<GEMM_GRID, 256, 0, stream>>>(B, W2T, nullptr, outdeg, A);
    pull_agg<1><<<AGG_GRID, 256, 0, stream>>>((unsigned int*)A, rowptr, csr_src,
                                              indeg, outdeg, b2, (unsigned int*)B);

    // Layer 3: A = bf16(agg(B)·id); Bf32 = relu(A@W3 + b3)  [f32 for pooling accuracy]
    pull_agg<0><<<AGG_GRID, 256, 0, stream>>>((unsigned int*)B, rowptr, csr_src,
                                              indeg, outdeg, nullptr, (unsigned int*)A);
    mfma_gemm<128, 128, 1, true><<<GEMM_GRID, 256, 0, stream>>>(A, W3T, b3, nullptr, Bf32);

    // Readout
    seg_pool<<<N_GRAPHS, 512, 0, stream>>>(Bf32, gstart, out);
    fc_kernel<<<N_GRAPHS, 128, 0, stream>>>(out, gamma, beta, Wf1, bf1, Wf2, bf2,
                                            out + (size_t)N_GRAPHS * H2);
}

// Round 10
// 246.958 us; speedup vs baseline: 1.4326x; 1.0784x over previous
//
#include <hip/hip_runtime.h>

#define N_NODES 50000
#define N_EDGES 800000
#define N_GRAPHS 128
#define IN_DIM 128
#define HID 256
#define H2 128
#define OUT_DIM 10
#define BN_EPS 1e-5f

#define NBUCK 196                              // dst>>8 buckets (50000/256)
#define K1_ITEMS 2048
#define NB_EDGE ((N_EDGES + K1_ITEMS - 1) / K1_ITEMS)   // 391
#define BND_BLOCKS ((N_NODES + 255) / 256)     // 196
#define CW1_BLOCKS  ((IN_DIM * HID) / 256)     // 128
#define CW2_BLOCKS  ((HID * H2) / 256)         // 128
#define CW3_BLOCKS  ((H2 * H2) / 256)          // 64

typedef __attribute__((ext_vector_type(8))) short short8_t;   // 8 bf16 (4 VGPRs)
typedef __attribute__((ext_vector_type(4))) float f32x4;

__device__ __forceinline__ unsigned short f2bf(float f) {
    union { float f; unsigned u; } x; x.f = f;
    unsigned r = x.u + 0x7fffu + ((x.u >> 16) & 1u);   // round-to-nearest-even
    return (unsigned short)(r >> 16);
}
__device__ __forceinline__ float bf2f(unsigned short h) {
    union { unsigned u; float f; } x; x.u = ((unsigned)h) << 16;
    return x.f;
}
__device__ __forceinline__ unsigned pack2(float a, float b) {
    return (unsigned)f2bf(a) | ((unsigned)f2bf(b) << 16);
}

__device__ __forceinline__ void convw_body(const float* __restrict__ W,
        unsigned short* __restrict__ WT, int K, int NOUT, int i) {
    int k = i / NOUT, n = i - k * NOUT;
    WT[(size_t)n * K + k] = f2bf(W[i]);
}

// ---- K1: per-block LDS histograms of dst>>8 and src>>8 | convw x3 | graph bounds ----
__global__ __launch_bounds__(256) void k1_hist(const int* __restrict__ src,
        const int* __restrict__ dst, int* __restrict__ cntD, int* __restrict__ cntS,
        const float* __restrict__ W1, const float* __restrict__ W2, const float* __restrict__ W3,
        unsigned short* __restrict__ W1T, unsigned short* __restrict__ W2T,
        unsigned short* __restrict__ W3T,
        const int* __restrict__ gid, int* __restrict__ gstart) {
    int bid = blockIdx.x, tid = threadIdx.x;
    if (bid < NB_EDGE) {
        __shared__ int hD[256], hS[256];
        hD[tid] = 0; hS[tid] = 0;
        __syncthreads();
        int base = bid * K1_ITEMS;
#pragma unroll
        for (int it = 0; it < 8; it++) {
            int e = base + it * 256 + tid;
            if (e < N_EDGES) {
                atomicAdd(&hD[dst[e] >> 8], 1);
                atomicAdd(&hS[src[e] >> 8], 1);
            }
        }
        __syncthreads();
        cntD[bid * 256 + tid] = hD[tid];
        cntS[bid * 256 + tid] = hS[tid];
        return;
    }
    bid -= NB_EDGE;
    if (bid < CW1_BLOCKS) { convw_body(W1, W1T, IN_DIM, HID, bid * 256 + tid); return; }
    bid -= CW1_BLOCKS;
    if (bid < CW2_BLOCKS) { convw_body(W2, W2T, HID, H2, bid * 256 + tid); return; }
    bid -= CW2_BLOCKS;
    if (bid < CW3_BLOCKS) { convw_body(W3, W3T, H2, H2, bid * 256 + tid); return; }
    bid -= CW3_BLOCKS;
    {   // graph segment starts (graph_ids sorted)
        int n = bid * 256 + tid;
        if (n >= N_NODES) return;
        int g = gid[n];
        int gp = (n == 0) ? -1 : gid[n - 1];
        for (int k = gp + 1; k <= g; k++) gstart[k] = n;
        if (n == N_NODES - 1)
            for (int k = g + 1; k <= N_GRAPHS; k++) gstart[k] = N_NODES;
    }
}

// ---- K2: scan count tables -> per-(block,bucket) offsets + bucket bases ----
__global__ __launch_bounds__(256) void k2_scan(const int* __restrict__ cntD,
        const int* __restrict__ cntS, int* __restrict__ offD, int* __restrict__ offS,
        int* __restrict__ baseD, int* __restrict__ baseS, int* __restrict__ rowptr) {
    int b = threadIdx.x;
    int runD = 0, runS = 0;
    for (int blk = 0; blk < NB_EDGE; blk++) {
        int cD = cntD[blk * 256 + b]; offD[blk * 256 + b] = runD; runD += cD;
        int cS = cntS[blk * 256 + b]; offS[blk * 256 + b] = runS; runS += cS;
    }
    __shared__ int ldsD[256], ldsS[256];
    ldsD[b] = runD; ldsS[b] = runS;
    __syncthreads();
    for (int off = 1; off < 256; off <<= 1) {
        int uD = (b >= off) ? ldsD[b - off] : 0;
        int uS = (b >= off) ? ldsS[b - off] : 0;
        __syncthreads();
        ldsD[b] += uD; ldsS[b] += uS;
        __syncthreads();
    }
    baseD[b] = ldsD[b] - runD;
    baseS[b] = ldsS[b] - runS;
    if (b == 0) rowptr[N_NODES] = N_EDGES;
}

// ---- K3: scatter edges into dst-buckets (uint2{dst,src}) and src-buckets (src) ----
__global__ __launch_bounds__(256) void k3_scatter(const int* __restrict__ src,
        const int* __restrict__ dst, const int* __restrict__ offD, const int* __restrict__ offS,
        const int* __restrict__ baseD, const int* __restrict__ baseS,
        uint2* __restrict__ bufD, int* __restrict__ bufS) {
    __shared__ int cD[256], cS[256];
    int bid = blockIdx.x, tid = threadIdx.x;
    cD[tid] = baseD[tid] + offD[bid * 256 + tid];
    cS[tid] = baseS[tid] + offS[bid * 256 + tid];
    __syncthreads();
    int base = bid * K1_ITEMS;
#pragma unroll
    for (int it = 0; it < 8; it++) {
        int e = base + it * 256 + tid;
        if (e < N_EDGES) {
            int d = dst[e], s = src[e];
            int pd = atomicAdd(&cD[d >> 8], 1);
            bufD[pd] = make_uint2((unsigned)d, (unsigned)s);
            int ps = atomicAdd(&cS[s >> 8], 1);
            bufS[ps] = s;
        }
    }
}

// ---- K45: fused per-bucket CSR build (dst) | outdeg + n_feat prescale (src) ----
__global__ __launch_bounds__(256) void k45_csr_prescale(const uint2* __restrict__ bufD,
        const int* __restrict__ baseD, int* __restrict__ indeg,
        int* __restrict__ rowptr, int* __restrict__ csr_src,
        const int* __restrict__ bufS, const int* __restrict__ baseS,
        const float* __restrict__ n_feat, int* __restrict__ outdeg,
        unsigned int* __restrict__ Xs) {
    int bid = blockIdx.x, t = threadIdx.x;
    if (bid < NBUCK) {
        // per dst-bucket: indeg, rowptr, csr_src (contiguous streams, LDS only)
        __shared__ int cnt[256], lds[256], curs[256];
        int b = bid;
        int eb = baseD[b], ee = baseD[b + 1];
        cnt[t] = 0;
        __syncthreads();
        for (int e = eb + t; e < ee; e += 256)
            atomicAdd(&cnt[bufD[e].x & 255], 1);
        __syncthreads();
        int v = cnt[t];
        lds[t] = v;
        __syncthreads();
        for (int off = 1; off < 256; off <<= 1) {
            int u = (t >= off) ? lds[t - off] : 0;
            __syncthreads();
            lds[t] += u;
            __syncthreads();
        }
        int n0 = b << 8;
        int ex = eb + lds[t] - v;
        if (n0 + t < N_NODES) {
            indeg[n0 + t] = v;
            rowptr[n0 + t] = ex;
        }
        curs[t] = ex;
        __syncthreads();
        for (int e = eb + t; e < ee; e += 256) {
            uint2 ed = bufD[e];
            int slot = atomicAdd(&curs[ed.x & 255], 1);
            csr_src[slot] = (int)ed.y;
        }
        return;
    }
    {   // per src-bucket: outdeg histogram + fused n_feat prescale -> Xs bf16
        __shared__ int cnt[256];
        __shared__ float od[256];
        int b = bid - NBUCK;
        int eb = baseS[b], ee = baseS[b + 1];
        cnt[t] = 0;
        __syncthreads();
        for (int e = eb + t; e < ee; e += 256)
            atomicAdd(&cnt[bufS[e] & 255], 1);
        __syncthreads();
        int n0 = b << 8;
        int nn = min(256, N_NODES - n0);
        if (t < nn) outdeg[n0 + t] = cnt[t];
        od[t] = rsqrtf(fmaxf((float)cnt[t], 1.0f));
        __syncthreads();
        int pc = t & 127;       // pair-column
        int rh = t >> 7;        // row parity
        for (int r = rh; r < nn; r += 2) {
            int row = n0 + r;
            float2 v = *reinterpret_cast<const float2*>(n_feat + (size_t)row * 128 + pc * 2);
            float s = od[r];
            Xs[(size_t)row * 64 + pc] = pack2(v.x * s, v.y * s);
        }
    }
}

// ---- pull aggregation: wave/node, paired rows, 8B/lane, scalar indices ----
// Main loop: 16 edges/iter, 8 uint2 in flight. Tail: ONE predicated batch
// (clamped scalar index loads + cndmask-zeroed lanes) -- no serial cleanup.
// MODE 0: out = bf16(acc * id)
// MODE 1: out = bf16(relu(acc*id + bias) * od)   (pre-scales for next layer)
template<int MODE>
__global__ __launch_bounds__(256) void pull_agg(const unsigned int* __restrict__ X,
        const int* __restrict__ rowptr, const int* __restrict__ csr_src,
        const int* __restrict__ indeg, const int* __restrict__ outdeg,
        const float* __restrict__ bias, unsigned int* __restrict__ out) {
    int lane = threadIdx.x & 63;
    int n = blockIdx.x * 4 + (threadIdx.x >> 6);
    n = __builtin_amdgcn_readfirstlane(n);     // wave-uniform -> scalar loads
    if (n >= N_NODES) return;
    int l32 = lane & 31;
    int half = lane >> 5;
    int beg = rowptr[n];
    int cnt = rowptr[n + 1] - beg;
    const int* ep = csr_src + beg;
    float a0 = 0.f, a1 = 0.f, a2 = 0.f, a3 = 0.f;
    int voff = l32 << 1;

    auto acc = [&](uint2 u) {
        a0 += bf2f((unsigned short)(u.x & 0xffff));
        a1 += bf2f((unsigned short)(u.x >> 16));
        a2 += bf2f((unsigned short)(u.y & 0xffff));
        a3 += bf2f((unsigned short)(u.y >> 16));
    };

    int j = 0;
    for (; j + 16 <= cnt; j += 16) {
        uint2 u[8];
#pragma unroll
        for (int q = 0; q < 8; q++) {
            int sa = ep[j + 2 * q], sb = ep[j + 2 * q + 1];
            int s = half ? sb : sa;
            u[q] = *reinterpret_cast<const uint2*>(X + ((size_t)s << 6) + voff);
        }
#pragma unroll
        for (int q = 0; q < 8; q++) acc(u[q]);
    }
    if (j < cnt) {   // single predicated batch covers the whole tail (<=15 edges)
        uint2 u[8];
        int last = cnt - 1;
#pragma unroll
        for (int q = 0; q < 8; q++) {
            int ja = j + 2 * q, jb = ja + 1;
            int sa = ep[min(ja, last)], sb = ep[min(jb, last)];
            int s = half ? sb : sa;
            uint2 v = *reinterpret_cast<const uint2*>(X + ((size_t)s << 6) + voff);
            int jj = half ? jb : ja;
            bool ok = jj < cnt;
            u[q].x = ok ? v.x : 0u;    // bf16 0x0000 == 0.0f
            u[q].y = ok ? v.y : 0u;
        }
#pragma unroll
        for (int q = 0; q < 8; q++) acc(u[q]);
    }

    a0 += __shfl_xor(a0, 32);
    a1 += __shfl_xor(a1, 32);
    a2 += __shfl_xor(a2, 32);
    a3 += __shfl_xor(a3, 32);

    if (lane < 32) {
        float id = rsqrtf(fmaxf((float)indeg[n], 1.0f));
        float v0 = a0 * id, v1 = a1 * id, v2 = a2 * id, v3 = a3 * id;
        if (MODE == 1) {
            float odv = rsqrtf(fmaxf((float)outdeg[n], 1.0f));
            float4 bv = *reinterpret_cast<const float4*>(bias + l32 * 4);
            v0 = fmaxf(v0 + bv.x, 0.f) * odv;
            v1 = fmaxf(v1 + bv.y, 0.f) * odv;
            v2 = fmaxf(v2 + bv.z, 0.f) * odv;
            v3 = fmaxf(v3 + bv.w, 0.f) * odv;
        }
        uint2 o = make_uint2(pack2(v0, v1), pack2(v2, v3));
        *reinterpret_cast<uint2*>(out + (size_t)n * 64 + voff) = o;
    }
}

// ---------------- MFMA bf16 GEMM, B-resident-in-registers, A streamed ----------------
// out[M,NOUT] = A[M,K] @ W[K,NOUT].  WT: bf16 [NOUT][K] (= W^T).
// EPI 1: bias+relu (aux=bias[NOUT])   EPI 2: row-scale by rsqrt(outdeg) (auxi=outdeg)
// F32OUT: write float (numeric headroom for the pooled layer).
template<int K, int NOUT, int EPI, bool F32OUT>
__global__ __launch_bounds__(256) void mfma_gemm(const unsigned short* __restrict__ A,
        const unsigned short* __restrict__ WT, const float* __restrict__ aux,
        const int* __restrict__ auxi, void* __restrict__ outv) {
    constexpr int KK  = K / 32;      // MFMA k-steps
    constexpr int NBW = NOUT / 64;   // 16-col blocks per wave (4 or 2)
    int wave = threadIdx.x >> 6;
    int lane = threadIdx.x & 63;
    int col0 = lane & 15;
    int kgrp = (lane >> 4) * 8;
    int wcol = wave * NBW * 16;

    short8_t b[NBW][KK];
    {
        const unsigned short* wbase = WT + (size_t)(wcol + col0) * K + kgrp;
#pragma unroll
        for (int n = 0; n < NBW; n++)
#pragma unroll
            for (int kk = 0; kk < KK; kk++)
                b[n][kk] = *reinterpret_cast<const short8_t*>(
                    wbase + (size_t)n * 16 * K + kk * 32);
    }
    float bv[NBW];
    if (EPI == 1) {
#pragma unroll
        for (int n = 0; n < NBW; n++) bv[n] = aux[wcol + n * 16 + col0];
    }

    constexpr int NT = N_NODES / 16;   // 3125 row tiles, exact
    for (int rt = blockIdx.x; rt < NT; rt += gridDim.x) {
        const unsigned short* ap = A + (size_t)(rt * 16 + col0) * K + kgrp;
        short8_t a[KK];
#pragma unroll
        for (int kk = 0; kk < KK; kk++)
            a[kk] = *reinterpret_cast<const short8_t*>(ap + kk * 32);

        f32x4 acc[NBW];
#pragma unroll
        for (int n = 0; n < NBW; n++) acc[n] = f32x4{0.f, 0.f, 0.f, 0.f};
#pragma unroll
        for (int kk = 0; kk < KK; kk++)
#pragma unroll
            for (int n = 0; n < NBW; n++)
                acc[n] = __builtin_amdgcn_mfma_f32_16x16x32_bf16(a[kk], b[n][kk], acc[n], 0, 0, 0);

        // C/D layout: col = lane&15, row = (lane>>4)*4 + reg
        int rbase = rt * 16 + ((lane >> 4) << 2);
        float rs[4];
        if (EPI == 2) {
#pragma unroll
            for (int j = 0; j < 4; j++)
                rs[j] = rsqrtf(fmaxf((float)auxi[rbase + j], 1.0f));
        }
#pragma unroll
        for (int n = 0; n < NBW; n++) {
            int col = wcol + n * 16 + col0;
#pragma unroll
            for (int j = 0; j < 4; j++) {
                float v = acc[n][j];
                if (EPI == 1) v = fmaxf(v + bv[n], 0.f);
                if (EPI == 2) v = v * rs[j];
                if (F32OUT)
                    ((float*)outv)[(size_t)(rbase + j) * NOUT + col] = v;
                else
                    ((unsigned short*)outv)[(size_t)(rbase + j) * NOUT + col] = f2bf(v);
            }
        }
    }
}

// ---------------- sum pooling over contiguous segments (f32 in, f32 out) ----------
__global__ __launch_bounds__(512) void seg_pool(const float* __restrict__ X,
        const int* __restrict__ gstart, float* __restrict__ emb) {
    int g = blockIdx.x;
    int lane = threadIdx.x & 63;      // 2 cols per lane
    int stripe = threadIdx.x >> 6;    // 0..7
    int beg = gstart[g], end = gstart[g + 1];
    float ax = 0.f, ay = 0.f;
    for (int r = beg + stripe; r < end; r += 8) {
        float2 v = *reinterpret_cast<const float2*>(X + (size_t)r * 128 + lane * 2);
        ax += v.x; ay += v.y;
    }
    __shared__ float bufx[8][64], bufy[8][64];
    bufx[stripe][lane] = ax;
    bufy[stripe][lane] = ay;
    __syncthreads();
    if (stripe == 0) {
        float sx = 0.f, sy = 0.f;
#pragma unroll
        for (int q = 0; q < 8; q++) { sx += bufx[q][lane]; sy += bufy[q][lane]; }
        emb[g * 128 + lane * 2]     = sx;
        emb[g * 128 + lane * 2 + 1] = sy;
    }
}

// ---------------- fused BN + FC head + log_softmax ----------------
__global__ __launch_bounds__(128) void fc_kernel(const float* __restrict__ emb,
        const float* __restrict__ gamma, const float* __restrict__ beta,
        const float* __restrict__ Wf1, const float* __restrict__ bf1,
        const float* __restrict__ Wf2, const float* __restrict__ bf2,
        float* __restrict__ out_ls) {
    __shared__ float h[H2];
    __shared__ float logits[OUT_DIM];
    int g = blockIdx.x;
    int j = threadIdx.x;
    float s = 0.f;
    for (int q = 0; q < N_GRAPHS; q++) s += emb[q * 128 + j];
    float mean = s * (1.0f / N_GRAPHS);
    float v = 0.f;
    for (int q = 0; q < N_GRAPHS; q++) {
        float d = emb[q * 128 + j] - mean;
        v += d * d;
    }
    v *= (1.0f / N_GRAPHS);
    float scale = rsqrtf(v + BN_EPS) * gamma[j];
    h[j] = (emb[g * 128 + j] - mean) * scale + beta[j];
    __syncthreads();
    float acc = bf1[j];
    for (int k = 0; k < H2; k++) acc += h[k] * Wf1[k * H2 + j];
    __syncthreads();
    h[j] = fmaxf(acc, 0.f);
    __syncthreads();
    if (j < OUT_DIM) {
        float a2 = bf2[j];
        for (int k = 0; k < H2; k++) a2 += h[k] * Wf2[k * OUT_DIM + j];
        logits[j] = a2;
    }
    __syncthreads();
    if (j < OUT_DIM) {
        float m = -1e30f;
        for (int o = 0; o < OUT_DIM; o++) m = fmaxf(m, logits[o]);
        float se = 0.f;
        for (int o = 0; o < OUT_DIM; o++) se += expf(logits[o] - m);
        out_ls[g * OUT_DIM + j] = logits[j] - m - logf(se);
    }
}

extern "C" void kernel_launch(void* const* d_in, const int* in_sizes, int n_in,
                              void* d_out, int out_size, void* d_ws, size_t ws_size,
                              hipStream_t stream) {
    const float* n_feat = (const float*)d_in[0];
    const int*   src    = (const int*)d_in[1];
    const int*   dst    = (const int*)d_in[2];
    const int*   gid    = (const int*)d_in[3];
    const float* W1     = (const float*)d_in[4];
    const float* b1     = (const float*)d_in[5];
    const float* W2     = (const float*)d_in[6];
    const float* b2     = (const float*)d_in[7];
    const float* W3     = (const float*)d_in[8];
    const float* b3     = (const float*)d_in[9];
    const float* Wf1    = (const float*)d_in[10];
    const float* bf1    = (const float*)d_in[11];
    const float* Wf2    = (const float*)d_in[12];
    const float* bf2    = (const float*)d_in[13];
    const float* gamma  = (const float*)d_in[14];
    const float* beta   = (const float*)d_in[15];
    float* out = (float*)d_out;

    char* ws = (char*)d_ws;
    size_t off = 0;
    auto alloc = [&](size_t bytes) {
        void* p = ws + off;
        off = (off + bytes + 255) & ~(size_t)255;
        return p;
    };
    int* cntD    = (int*)alloc((size_t)NB_EDGE * 256 * 4);
    int* cntS    = (int*)alloc((size_t)NB_EDGE * 256 * 4);
    int* offD    = (int*)alloc((size_t)NB_EDGE * 256 * 4);
    int* offS    = (int*)alloc((size_t)NB_EDGE * 256 * 4);
    int* baseD   = (int*)alloc(257 * 4);
    int* baseS   = (int*)alloc(257 * 4);
    int* indeg   = (int*)alloc((size_t)N_NODES * 4);
    int* outdeg  = (int*)alloc((size_t)N_NODES * 4);
    int* rowptr  = (int*)alloc((size_t)(N_NODES + 1) * 4);
    int* gstart  = (int*)alloc((size_t)(N_GRAPHS + 1) * 4);
    uint2* bufD  = (uint2*)alloc((size_t)N_EDGES * 8);
    int* bufS    = (int*)alloc((size_t)N_EDGES * 4);
    int* csr_src = (int*)alloc((size_t)N_EDGES * 4);
    unsigned short* Xs  = (unsigned short*)alloc((size_t)N_NODES * 128 * 2);
    unsigned short* A   = (unsigned short*)alloc((size_t)N_NODES * 128 * 2);
    unsigned short* B   = (unsigned short*)alloc((size_t)N_NODES * 256 * 2);  // also f32 [N,128]
    unsigned short* W1T = (unsigned short*)alloc((size_t)IN_DIM * HID * 2);
    unsigned short* W2T = (unsigned short*)alloc((size_t)HID * H2 * 2);
    unsigned short* W3T = (unsigned short*)alloc((size_t)H2 * H2 * 2);
    float* Bf32 = (float*)B;   // N*256*2 bytes == N*128*4 bytes

    // preprocessing: zero global atomics
    k1_hist<<<NB_EDGE + CW1_BLOCKS + CW2_BLOCKS + CW3_BLOCKS + BND_BLOCKS, 256, 0, stream>>>(
        src, dst, cntD, cntS, W1, W2, W3, W1T, W2T, W3T, gid, gstart);
    k2_scan<<<1, 256, 0, stream>>>(cntD, cntS, offD, offS, baseD, baseS, rowptr);
    k3_scatter<<<NB_EDGE, 256, 0, stream>>>(src, dst, offD, offS, baseD, baseS, bufD, bufS);
    k45_csr_prescale<<<NBUCK * 2, 256, 0, stream>>>(bufD, baseD, indeg, rowptr, csr_src,
                                                    bufS, baseS, n_feat, outdeg,
                                                    (unsigned int*)Xs);

    const int AGG_GRID = (N_NODES + 3) / 4;
    const int GEMM_GRID = 1024;

    // Layer 1: A = bf16(agg(Xs)·id); B = bf16(relu(A@W1 + b1))  [N,256]
    pull_agg<0><<<AGG_GRID, 256, 0, stream>>>((unsigned int*)Xs, rowptr, csr_src,
                                              indeg, outdeg, nullptr, (unsigned int*)A);
    mfma_gemm<128, 256, 1, false><<<GEMM_GRID, 256, 0, stream>>>(A, W1T, b1, nullptr, B);

    // Layer 2: A = bf16((X1@W2)·od); B = bf16(relu(agg(A)·id + b2)·od)
    mfma_gemm<256, 128, 2, false><<<GEMM_GRID, 256, 0, stream>>>(B, W2T, nullptr, outdeg, A);
    pull_agg<1><<<AGG_GRID, 256, 0, stream>>>((unsigned int*)A, rowptr, csr_src,
                                              indeg, outdeg, b2, (unsigned int*)B);

    // Layer 3: A = bf16(agg(B)·id); Bf32 = relu(A@W3 + b3)  [f32 for pooling accuracy]
    pull_agg<0><<<AGG_GRID, 256, 0, stream>>>((unsigned int*)B, rowptr, csr_src,
                                              indeg, outdeg, nullptr, (unsigned int*)A);
    mfma_gemm<128, 128, 1, true><<<GEMM_GRID, 256, 0, stream>>>(A, W3T, b3, nullptr, Bf32);

    // Readout
    seg_pool<<<N_GRAPHS, 512, 0, stream>>>(Bf32, gstart, out);
    fc_kernel<<<N_GRAPHS, 128, 0, stream>>>(out, gamma, beta, Wf1, bf1, Wf2, bf2,
                                            out + (size_t)N_GRAPHS * H2);
}